// Round 12
// baseline (262.037 us; speedup 1.0000x reference)
//
#include <hip/hip_runtime.h>
#include <hip/hip_bf16.h>

#define N_V 100000
#define N_E 20000
#define N_P 1600000
#define FDIM 128
#define HDIM 128
#define BN_EPS 1e-5f

// ---- bucket/sort geometry ----
#define SORT_C 4096
#define SORT_BLOCKS ((N_P + SORT_C - 1) / SORT_C)   // 391
#define NB_E 313                   // edge buckets (64 edges each)
#define EB_SHIFT 6
#define EB_REGION 9216             // slots per edge bucket region
#define EB_SORT 5888               // max valid entries per bucket (mean 5112)
#define NB_V 391                   // vertex buckets (256 vertices each)
#define VB_SHIFT 8
#define VB_REGION 8192
#define VB_SORT 4608               // max valid entries per bucket (mean 4096)
#define SENTINEL 0xFFFFFFFFu

#define EIDX_CAP 192   // per-wave LDS index buffer, edges (mean deg 80)
#define VIDX_CAP 64    // per-wave LDS index buffer, vertices (mean deg 16)

#define GEMM_BLOCKS 625
#define WT_STRIDE 136   // 128 + 8 bf16 pad -> 2-way-only LDS conflicts
#define BN_BLOCKS 400
#define BN_RPB 250

typedef __attribute__((ext_vector_type(8))) short short8;
typedef __attribute__((ext_vector_type(4))) float floatx4;

__device__ __forceinline__ float bf_lo(unsigned u) {
    return __uint_as_float(u << 16);
}
__device__ __forceinline__ float bf_hi(unsigned u) {
    return __uint_as_float(u & 0xffff0000u);
}
// fp32 -> bf16 bits, round-to-nearest-even
__device__ __forceinline__ unsigned short f2bf(float f) {
    unsigned u = __float_as_uint(f);
    return (unsigned short)((u + 0x7fffu + ((u >> 16) & 1u)) >> 16);
}

// accumulate 4 bf16 channels from one uint2 into s[0..3]
__device__ __forceinline__ void acc4(float* s, const uint2& u) {
    s[0] += bf_lo(u.x); s[1] += bf_hi(u.x);
    s[2] += bf_lo(u.y); s[3] += bf_hi(u.y);
}

// accumulate 8 bf16 channels from one uint4 into s[0..7]
__device__ __forceinline__ void acc8(float* s, const uint4& u) {
    s[0] += bf_lo(u.x); s[1] += bf_hi(u.x);
    s[2] += bf_lo(u.y); s[3] += bf_hi(u.y);
    s[4] += bf_lo(u.z); s[5] += bf_hi(u.z);
    s[6] += bf_lo(u.w); s[7] += bf_hi(u.w);
}

// ===========================================================================
// K1 shared-memory union.  [R11->R12: R11's two-way fuse had a 45 KB union
// (dual-direction sort) capping the whole kernel at 3 blocks/CU, 16%
// occupancy.  Splitting the sort into per-direction bodies shrinks the
// union to gemm's 34.8 KB -> 4 blocks/CU.  Cost: eid/vid read twice (~2us).]
// ===========================================================================
union SmemK1 {
    struct {
        unsigned short WTs[FDIM * WT_STRIDE];                  // 34.8 KB
    } g;
    struct {
        unsigned stage[SORT_C];                                // 16 KB
        int hist[NB_E], cur[NB_E], offs[NB_E], gbase[NB_E];    //  5 KB
        int partial[256];
    } se;                                                      // ~22 KB
    struct {
        unsigned stage[SORT_C];                                // 16 KB
        int hist[NB_V], cur[NB_V], offs[NB_V], gbase[NB_V];    //  6.3 KB
        int partial[256];
    } sv;                                                      // ~23.3 KB
};

union SmemBnCsr {
    struct {
        unsigned B[EB_SORT];        // max(EB_SORT, VB_SORT)
        int hist[256];              // max(64, 256)
        int offs[257];
        int cur[256];
    } c;                            // ~26 KB
    struct {
        float ls[128], lss[128];
    } b;
};

// ---------------------------------------------------------------------------
// gemm body: h = X @ W + b via bf16 MFMA, computed as C^T = W^T · X^T.
// ---------------------------------------------------------------------------
__device__ void gemm_body(int bid, unsigned short* WTs,
                          const float* __restrict__ X,
                          const float* __restrict__ W,
                          const float* __restrict__ bias,
                          unsigned* __restrict__ h_u) {
    const int t = threadIdx.x;
    for (int idx = t; idx < FDIM * HDIM; idx += 256) {
        const int k = idx >> 7, m = idx & 127;
        WTs[m * WT_STRIDE + k] = f2bf(W[idx]);
    }
    __syncthreads();

    const int wave = t >> 6, lane = t & 63;
    const int quad = lane >> 4, sub = lane & 15;
    const int nstrips = N_V / 16;  // 6250, exact

    for (int s = bid * 4 + wave; s < nstrips; s += GEMM_BLOCKS * 4) {
        const int row0 = s * 16;
        short8 xf[4];
        const float* xp = X + (size_t)(row0 + sub) * FDIM + quad * 8;
        #pragma unroll
        for (int kt = 0; kt < 4; ++kt) {
            const float4 a = *(const float4*)(xp + kt * 32);
            const float4 b2 = *(const float4*)(xp + kt * 32 + 4);
            short8 f;
            f[0] = (short)f2bf(a.x);  f[1] = (short)f2bf(a.y);
            f[2] = (short)f2bf(a.z);  f[3] = (short)f2bf(a.w);
            f[4] = (short)f2bf(b2.x); f[5] = (short)f2bf(b2.y);
            f[6] = (short)f2bf(b2.z); f[7] = (short)f2bf(b2.w);
            xf[kt] = f;
        }
        #pragma unroll
        for (int tile = 0; tile < 8; ++tile) {
            floatx4 acc = {0.f, 0.f, 0.f, 0.f};
            const unsigned short* wp =
                WTs + (tile * 16 + sub) * WT_STRIDE + quad * 8;
            #pragma unroll
            for (int kt = 0; kt < 4; ++kt) {
                const short8 af = *(const short8*)(wp + kt * 32);
                acc = __builtin_amdgcn_mfma_f32_16x16x32_bf16(af, xf[kt], acc,
                                                              0, 0, 0);
            }
            const int ch = tile * 16 + quad * 4;
            const float4 bb = *(const float4*)(bias + ch);
            const float c0 = acc[0] + bb.x, c1 = acc[1] + bb.y;
            const float c2 = acc[2] + bb.z, c3 = acc[3] + bb.w;
            const unsigned lo = (unsigned)f2bf(c0) | ((unsigned)f2bf(c1) << 16);
            const unsigned hi = (unsigned)f2bf(c2) | ((unsigned)f2bf(c3) << 16);
            uint2* dst = (uint2*)(h_u + (size_t)(row0 + sub) * 64 + (ch >> 1));
            *dst = make_uint2(lo, hi);
        }
    }
}

// ---------------------------------------------------------------------------
// single-direction sort body: LDS-staged chunk sort, line-aligned full-line
// flush.  [R9 lesson: direct global scatter = 16x write amplification;
// bucket+full-line-flush is the right structure.]
// EDGE: key=eid, val=vid, pk=((k&63)<<17)|v ; else key=vid, val=eid,
// pk=((k&255)<<15)|v.
// ---------------------------------------------------------------------------
template <int NB, int BSHIFT, int REGION, bool EDGE>
__device__ void sort_dir_body(int bid, unsigned* stage, int* hist, int* cur,
                              int* offs, int* gbase, int* partial,
                              const int* __restrict__ keys,
                              const int* __restrict__ vals,
                              int* __restrict__ gcnt,
                              unsigned* __restrict__ part) {
    const int t = threadIdx.x;
    const int p0 = bid * SORT_C;
    const int n = min(SORT_C, N_P - p0);         // always divisible by 4
    const int n4 = n >> 2;
    const int4* k4p = (const int4*)(keys + p0);
    const int4* v4p = (const int4*)(vals + p0);

    for (int k = t; k < NB; k += 256) hist[k] = 0;
    __syncthreads();
    for (int i = t; i < n4; i += 256) {
        const int4 k4 = k4p[i];
        atomicAdd(&hist[((unsigned)k4.x) >> BSHIFT], 1);
        atomicAdd(&hist[((unsigned)k4.y) >> BSHIFT], 1);
        atomicAdd(&hist[((unsigned)k4.z) >> BSHIFT], 1);
        atomicAdd(&hist[((unsigned)k4.w) >> BSHIFT], 1);
    }
    __syncthreads();
    // block-wide exclusive scan of hist
    {
        constexpr int G = (NB + 255) / 256;
        int loc[G]; int s = 0;
        #pragma unroll
        for (int g = 0; g < G; ++g) {
            int idx = t * G + g; loc[g] = s;
            if (idx < NB) s += hist[idx];
        }
        partial[t] = s;
        __syncthreads();
        for (int d = 1; d < 256; d <<= 1) {
            int x = (t >= d) ? partial[t - d] : 0;
            __syncthreads(); partial[t] += x; __syncthreads();
        }
        const int base = t ? partial[t - 1] : 0;
        #pragma unroll
        for (int g = 0; g < G; ++g) {
            int idx = t * G + g;
            if (idx < NB) { offs[idx] = base + loc[g]; cur[idx] = base + loc[g]; }
        }
        __syncthreads();
    }
    // place (4 entries per thread, int4 loads)
    for (int i = t; i < n4; i += 256) {
        const int4 k4 = k4p[i];
        const int4 v4 = v4p[i];
        #pragma unroll
        for (int q = 0; q < 4; ++q) {
            const int kk = (q == 0) ? k4.x : (q == 1) ? k4.y : (q == 2) ? k4.z : k4.w;
            const int vv = (q == 0) ? v4.x : (q == 1) ? v4.y : (q == 2) ? v4.z : v4.w;
            const unsigned pk = EDGE
                ? (((unsigned)(kk & 63) << 17) | (unsigned)vv)
                : (((unsigned)(kk & 255) << 15) | (unsigned)vv);
            stage[atomicAdd(&cur[(unsigned)kk >> BSHIFT], 1)] = pk;
        }
    }
    __syncthreads();
    // allocate line-aligned global space
    for (int k = t; k < NB; k += 256) {
        const int c = hist[k];
        gbase[k] = c ? atomicAdd(&gcnt[k], (c + 15) & ~15) : 0;
    }
    __syncthreads();
    // flush (uint4 writes; cpad multiple of 16, dst 64B aligned)
    for (int k = t >> 3; k < NB; k += 32) {
        const int c = hist[k];
        if (c == 0) continue;
        int cpad = (c + 15) & ~15;
        const int gb = gbase[k];
        if (gb >= REGION) continue;
        cpad = min(cpad, REGION - gb);
        unsigned* dst = part + (size_t)k * REGION + gb;
        const int lo = offs[k];
        for (int j = (t & 7) * 4; j + 3 < cpad; j += 32) {
            uint4 w;
            w.x = (j + 0 < c) ? stage[lo + j + 0] : SENTINEL;
            w.y = (j + 1 < c) ? stage[lo + j + 1] : SENTINEL;
            w.z = (j + 2 < c) ? stage[lo + j + 2] : SENTINEL;
            w.w = (j + 3 < c) ? stage[lo + j + 3] : SENTINEL;
            *(uint4*)(dst + j) = w;
        }
    }
}

// ---------------------------------------------------------------------------
// K1: gemm (0..624) || sortE (625..1015) || sortV (1016..1406).  Three
// mutually independent input->workspace chains fused for concurrency;
// per-direction sort bodies keep the LDS union at gemm's 34.8 KB.
// ---------------------------------------------------------------------------
__global__ __launch_bounds__(256) void k_gemm_sort(
    const float* __restrict__ X, const float* __restrict__ W,
    const float* __restrict__ bias, unsigned* __restrict__ h_u,
    const int* __restrict__ vid, const int* __restrict__ eid,
    int* __restrict__ gcntE, int* __restrict__ gcntV,
    unsigned* __restrict__ partE, unsigned* __restrict__ partV) {
    __shared__ __align__(16) SmemK1 sm;
    const int b = blockIdx.x;
    if (b < GEMM_BLOCKS) {
        gemm_body(b, sm.g.WTs, X, W, bias, h_u);
    } else if (b < GEMM_BLOCKS + SORT_BLOCKS) {
        sort_dir_body<NB_E, EB_SHIFT, EB_REGION, true>(
            b - GEMM_BLOCKS, sm.se.stage, sm.se.hist, sm.se.cur, sm.se.offs,
            sm.se.gbase, sm.se.partial, eid, vid, gcntE, partE);
    } else {
        sort_dir_body<NB_V, VB_SHIFT, VB_REGION, false>(
            b - GEMM_BLOCKS - SORT_BLOCKS, sm.sv.stage, sm.sv.hist, sm.sv.cur,
            sm.sv.offs, sm.sv.gbase, sm.sv.partial, vid, eid, gcntV, partV);
    }
}

// ---------------------------------------------------------------------------
// bn_stats body: per-channel sum & sumsq of bf16 h.  uint4/lane.
// ---------------------------------------------------------------------------
__device__ void bn_body(int bid, float* ls, float* lss,
                        const unsigned* __restrict__ h_u,
                        float* __restrict__ sums) {
    const int t = threadIdx.x;
    const int c8 = t & 15;            // channel octet: ch 8*c8 .. 8*c8+7
    const int rw = t >> 4;            // 16 row lanes
    const int r0 = bid * BN_RPB;
    const int r1 = min(r0 + BN_RPB, N_V);
    float s[8] = {0.f,0.f,0.f,0.f,0.f,0.f,0.f,0.f};
    float ss[8] = {0.f,0.f,0.f,0.f,0.f,0.f,0.f,0.f};
    for (int r = r0 + rw; r < r1; r += 16) {
        const uint4 u = *(const uint4*)(h_u + (size_t)r * 64 + c8 * 4);
        const float x0 = bf_lo(u.x), x1 = bf_hi(u.x);
        const float x2 = bf_lo(u.y), x3 = bf_hi(u.y);
        const float x4 = bf_lo(u.z), x5 = bf_hi(u.z);
        const float x6 = bf_lo(u.w), x7 = bf_hi(u.w);
        s[0]+=x0; ss[0]+=x0*x0;  s[1]+=x1; ss[1]+=x1*x1;
        s[2]+=x2; ss[2]+=x2*x2;  s[3]+=x3; ss[3]+=x3*x3;
        s[4]+=x4; ss[4]+=x4*x4;  s[5]+=x5; ss[5]+=x5*x5;
        s[6]+=x6; ss[6]+=x6*x6;  s[7]+=x7; ss[7]+=x7*x7;
    }
    #pragma unroll
    for (int k = 0; k < 8; ++k) {
        s[k]  += __shfl_xor(s[k], 16);  s[k]  += __shfl_xor(s[k], 32);
        ss[k] += __shfl_xor(ss[k], 16); ss[k] += __shfl_xor(ss[k], 32);
    }
    for (int k = t; k < 128; k += 256) { ls[k] = 0.f; lss[k] = 0.f; }
    __syncthreads();
    if ((t & 63) < 16) {
        #pragma unroll
        for (int k = 0; k < 8; ++k) {
            atomicAdd(&ls[c8 * 8 + k], s[k]);
            atomicAdd(&lss[c8 * 8 + k], ss[k]);
        }
    }
    __syncthreads();
    if (t < 128) {
        atomicAdd(&sums[t],       ls[t]);
        atomicAdd(&sums[128 + t], lss[t]);
    }
}

// ---------------------------------------------------------------------------
// csr body: bucket region -> compact sorted CSR.  Sentinels skipped inline,
// uint4 reads, uint4 B write-out.  [R7 lesson: keep sort->register-reduce;
// LDS-atomic accumulation is 27x slower.]
// ---------------------------------------------------------------------------
template <int NKEY, int PACK_SHIFT, int CAP, int REGION, int STRIDE>
__device__ void csr_body(int bkt, const unsigned* __restrict__ part,
                         const int* __restrict__ gcnt, int nkeys_total,
                         int* __restrict__ segoff, int* __restrict__ segcnt,
                         unsigned* __restrict__ csr,
                         unsigned* B, int* hist, int* offs, int* cur) {
    const int t = threadIdx.x;
    const unsigned mask = (1u << PACK_SHIFT) - 1u;
    const int tot = min(gcnt[bkt], REGION);
    const int tot4 = tot >> 2;
    const unsigned* src = part + (size_t)bkt * REGION;

    for (int k = t; k < NKEY; k += 256) { hist[k] = 0; cur[k] = 0; }
    __syncthreads();
    for (int i = t; i < tot4; i += 256) {
        const uint4 a = ((const uint4*)src)[i];
        if (a.x != SENTINEL) atomicAdd(&hist[a.x >> PACK_SHIFT], 1);
        if (a.y != SENTINEL) atomicAdd(&hist[a.y >> PACK_SHIFT], 1);
        if (a.z != SENTINEL) atomicAdd(&hist[a.z >> PACK_SHIFT], 1);
        if (a.w != SENTINEL) atomicAdd(&hist[a.w >> PACK_SHIFT], 1);
    }
    for (int i = tot4 * 4 + t; i < tot; i += 256) {
        const unsigned a = src[i];
        if (a != SENTINEL) atomicAdd(&hist[a >> PACK_SHIFT], 1);
    }
    __syncthreads();
    if (t == 0) {
        int acc = 0;
        for (int k = 0; k < NKEY; ++k) { offs[k] = acc; acc += hist[k]; }
        offs[NKEY] = acc;
    }
    __syncthreads();
    for (int i = t; i < tot4; i += 256) {
        const uint4 a = ((const uint4*)src)[i];
        #pragma unroll
        for (int q = 0; q < 4; ++q) {
            const unsigned av = (q == 0) ? a.x : (q == 1) ? a.y : (q == 2) ? a.z : a.w;
            if (av != SENTINEL) {
                const int k = av >> PACK_SHIFT;
                const int pos = offs[k] + atomicAdd(&cur[k], 1);
                if (pos < CAP) B[pos] = av & mask;
            }
        }
    }
    for (int i = tot4 * 4 + t; i < tot; i += 256) {
        const unsigned av = src[i];
        if (av != SENTINEL) {
            const int k = av >> PACK_SHIFT;
            const int pos = offs[k] + atomicAdd(&cur[k], 1);
            if (pos < CAP) B[pos] = av & mask;
        }
    }
    __syncthreads();
    const int total = min(offs[NKEY], CAP);
    unsigned* dst = csr + (size_t)bkt * STRIDE;
    for (int i = t * 4; i + 3 < total; i += 1024)
        *(uint4*)(dst + i) = *(const uint4*)(&B[i]);
    for (int i = (total & ~3) + t; i < total; i += 256) dst[i] = B[i];
    for (int k = t; k < NKEY; k += 256) {
        const int g = bkt * NKEY + k;
        if (g < nkeys_total) {
            const int o0 = min(offs[k], CAP);
            const int o1 = min(offs[k + 1], CAP);
            segoff[g] = bkt * STRIDE + o0;
            segcnt[g] = o1 - o0;
        }
    }
}

// ---------------------------------------------------------------------------
// K2: bn_stats (0..399) || csrE (400..712) || csrV (713..1103).  All three
// depend only on K1's outputs and are mutually independent.
// ---------------------------------------------------------------------------
__global__ __launch_bounds__(256) void k_bn_csr(
    const unsigned* __restrict__ h_u, float* __restrict__ sums,
    const unsigned* __restrict__ partE, const int* __restrict__ gcntE,
    int* __restrict__ eoff, int* __restrict__ ecnt, unsigned* __restrict__ csrE,
    const unsigned* __restrict__ partV, const int* __restrict__ gcntV,
    int* __restrict__ voff, int* __restrict__ vcnt, unsigned* __restrict__ csrV) {
    __shared__ __align__(16) SmemBnCsr sm;
    const int b = blockIdx.x;
    if (b < BN_BLOCKS) {
        bn_body(b, sm.b.ls, sm.b.lss, h_u, sums);
    } else if (b < BN_BLOCKS + NB_E) {
        csr_body<64, 17, EB_SORT, EB_REGION, EB_SORT>(
            b - BN_BLOCKS, partE, gcntE, N_E, eoff, ecnt, csrE,
            sm.c.B, sm.c.hist, sm.c.offs, sm.c.cur);
    } else {
        csr_body<256, 15, VB_SORT, VB_REGION, VB_SORT>(
            b - BN_BLOCKS - NB_E, partV, gcntV, N_V, voff, vcnt, csrV,
            sm.c.B, sm.c.hist, sm.c.offs, sm.c.cur);
    }
}

// ---------------------------------------------------------------------------
// Kernel F: per-edge gather-reduce, CHANNEL-HALF split across XCD groups.
// blockIdx%8 selects the XCD; XCDs 0-3 process channels 0..63, XCDs 4-7
// channels 64..127 -> per-XCD L2 holds 128 B/row.  [measured R5/R6/R8]
// BN finalize (scale/shift) computed inline in the epilogue from sums/
// gamma/beta (R12: removes the k_bn_final launch; reads are L2-hot).
// ---------------------------------------------------------------------------
__global__ __launch_bounds__(256) void k_edge_gather(
    const unsigned* __restrict__ h_u, const unsigned* __restrict__ csrE,
    const int* __restrict__ eoff, const int* __restrict__ ecnt,
    const float* __restrict__ sums, const float* __restrict__ gamma,
    const float* __restrict__ beta, unsigned* __restrict__ xe_u) {
    __shared__ int ib[4][EIDX_CAP];
    const int b = blockIdx.x;                   // 0 .. 2*(N_E/4)-1
    const int xcd = b & 7;
    const int half = xcd >> 2;                  // channel half 0/1
    const int grp = (b >> 3) * 4 + (xcd & 3);   // edge group 0..N_E/4-1
    const int wave = threadIdx.x >> 6;
    const int e = grp * 4 + wave;
    const int l = threadIdx.x & 63;
    const int rg = l >> 4, c = l & 15;          // row-in-group, channel-pair
    const int wbase = half * 32 + 2 * c;        // word offset within row
    int o = 0, n = 0;
    if (e < N_E) { o = eoff[e]; n = ecnt[e]; }
    const int nc = min(n, EIDX_CAP);
    int* mi = ib[wave];
    for (int i = l; i < nc; i += 64) mi[i] = (int)csrE[o + i];
    __syncthreads();

    float s[4] = {0.f, 0.f, 0.f, 0.f};
    int j = 0;
    for (; j + 31 < nc; j += 32) {
        const int r0 = mi[j + rg],      r1 = mi[j + 4 + rg];
        const int r2 = mi[j + 8 + rg],  r3 = mi[j + 12 + rg];
        const int r4 = mi[j + 16 + rg], r5 = mi[j + 20 + rg];
        const int r6 = mi[j + 24 + rg], r7 = mi[j + 28 + rg];
        const uint2 u0 = *(const uint2*)(h_u + (size_t)r0 * 64 + wbase);
        const uint2 u1 = *(const uint2*)(h_u + (size_t)r1 * 64 + wbase);
        const uint2 u2 = *(const uint2*)(h_u + (size_t)r2 * 64 + wbase);
        const uint2 u3 = *(const uint2*)(h_u + (size_t)r3 * 64 + wbase);
        const uint2 u4 = *(const uint2*)(h_u + (size_t)r4 * 64 + wbase);
        const uint2 u5 = *(const uint2*)(h_u + (size_t)r5 * 64 + wbase);
        const uint2 u6 = *(const uint2*)(h_u + (size_t)r6 * 64 + wbase);
        const uint2 u7 = *(const uint2*)(h_u + (size_t)r7 * 64 + wbase);
        acc4(s, u0); acc4(s, u1); acc4(s, u2); acc4(s, u3);
        acc4(s, u4); acc4(s, u5); acc4(s, u6); acc4(s, u7);
    }
    for (; j + 15 < nc; j += 16) {
        const int r0 = mi[j + rg],     r1 = mi[j + 4 + rg];
        const int r2 = mi[j + 8 + rg], r3 = mi[j + 12 + rg];
        const uint2 u0 = *(const uint2*)(h_u + (size_t)r0 * 64 + wbase);
        const uint2 u1 = *(const uint2*)(h_u + (size_t)r1 * 64 + wbase);
        const uint2 u2 = *(const uint2*)(h_u + (size_t)r2 * 64 + wbase);
        const uint2 u3 = *(const uint2*)(h_u + (size_t)r3 * 64 + wbase);
        acc4(s, u0); acc4(s, u1); acc4(s, u2); acc4(s, u3);
    }
    for (; j < nc; j += 4) {
        if (j + rg < nc) {
            const int r = mi[j + rg];
            const uint2 u = *(const uint2*)(h_u + (size_t)r * 64 + wbase);
            acc4(s, u);
        }
    }
    // overflow path (n > EIDX_CAP), statistically negligible but correct
    for (int jj = nc; jj < n; jj += 4) {
        if (jj + rg < n) {
            const int r = (int)csrE[o + jj + rg];
            const uint2 u = *(const uint2*)(h_u + (size_t)r * 64 + wbase);
            acc4(s, u);
        }
    }
    #pragma unroll
    for (int k = 0; k < 4; ++k) {
        s[k] += __shfl_xor(s[k], 16);
        s[k] += __shfl_xor(s[k], 32);
    }
    if (e < N_E && rg == 0) {
        const float inv_n = 1.0f / (float)N_V;
        const float rc = (n > 0) ? (1.0f / (float)n) : 0.f;
        float m[4];
        #pragma unroll
        for (int q = 0; q < 4; ++q) {
            const int ch = half * 64 + c * 4 + q;
            float mv = 0.f;
            if (n > 0) {
                const float mu  = sums[ch] * inv_n;
                const float var = sums[128 + ch] * inv_n - mu * mu;
                const float inv = rsqrtf(var + BN_EPS);
                const float sc  = gamma[ch] * inv;
                const float sh  = beta[ch] - mu * sc;
                mv = sc * s[q] * rc + sh;
            }
            m[q] = mv;
        }
        uint2 pk;
        pk.x = (unsigned)f2bf(m[0]) | ((unsigned)f2bf(m[1]) << 16);
        pk.y = (unsigned)f2bf(m[2]) | ((unsigned)f2bf(m[3]) << 16);
        *(uint2*)(xe_u + (size_t)e * 64 + wbase) = pk;
    }
}

// ---------------------------------------------------------------------------
// Kernel G: per-vertex gather-reduce + ReLU.  Full-row uint4, one wave per
// vertex, LDS index prefetch, 16-row main loop.  [measured R6/R8/R10: ~48 us]
// ---------------------------------------------------------------------------
__global__ __launch_bounds__(256) void k_vert_gather(
    const unsigned* __restrict__ xe_u, const unsigned* __restrict__ csrV,
    const int* __restrict__ voff, const int* __restrict__ vcnt,
    float* __restrict__ out) {
    __shared__ int ib[4][VIDX_CAP];
    const int wave = threadIdx.x >> 6;
    const int v = blockIdx.x * 4 + wave;
    const int l = threadIdx.x & 63;
    const int g = l >> 4, c = l & 15;
    int o = 0, n = 0;
    if (v < N_V) { o = voff[v]; n = vcnt[v]; }
    const int nc = min(n, VIDX_CAP);
    int* mi = ib[wave];
    for (int i = l; i < nc; i += 64) mi[i] = (int)csrV[o + i];
    __syncthreads();

    float s[8] = {0.f, 0.f, 0.f, 0.f, 0.f, 0.f, 0.f, 0.f};
    int j = 0;
    for (; j + 15 < nc; j += 16) {
        const int r0 = mi[j + g],     r1 = mi[j + 4 + g];
        const int r2 = mi[j + 8 + g], r3 = mi[j + 12 + g];
        const uint4 u0 = *(const uint4*)(xe_u + (size_t)r0 * 64 + 4 * c);
        const uint4 u1 = *(const uint4*)(xe_u + (size_t)r1 * 64 + 4 * c);
        const uint4 u2 = *(const uint4*)(xe_u + (size_t)r2 * 64 + 4 * c);
        const uint4 u3 = *(const uint4*)(xe_u + (size_t)r3 * 64 + 4 * c);
        acc8(s, u0); acc8(s, u1); acc8(s, u2); acc8(s, u3);
    }
    for (; j < nc; j += 4) {
        if (j + g < nc) {
            const int r = mi[j + g];
            const uint4 u = *(const uint4*)(xe_u + (size_t)r * 64 + 4 * c);
            acc8(s, u);
        }
    }
    // overflow path (n > VIDX_CAP), statistically negligible but correct
    for (int jj = nc; jj < n; jj += 4) {
        if (jj + g < n) {
            const int r = (int)csrV[o + jj + g];
            const uint4 u = *(const uint4*)(xe_u + (size_t)r * 64 + 4 * c);
            acc8(s, u);
        }
    }
    #pragma unroll
    for (int k = 0; k < 8; ++k) {
        s[k] += __shfl_xor(s[k], 16);
        s[k] += __shfl_xor(s[k], 32);
    }
    if (v < N_V && g == 0) {
        const float rc = 1.0f / (float)max(n, 1);
        float4 r0, r1;
        r0.x = fmaxf(s[0] * rc, 0.f);
        r0.y = fmaxf(s[1] * rc, 0.f);
        r0.z = fmaxf(s[2] * rc, 0.f);
        r0.w = fmaxf(s[3] * rc, 0.f);
        r1.x = fmaxf(s[4] * rc, 0.f);
        r1.y = fmaxf(s[5] * rc, 0.f);
        r1.z = fmaxf(s[6] * rc, 0.f);
        r1.w = fmaxf(s[7] * rc, 0.f);
        ((float4*)out)[(size_t)v * 32 + 2 * c]     = r0;
        ((float4*)out)[(size_t)v * 32 + 2 * c + 1] = r1;
    }
}

// ---------------------------------------------------------------------------
extern "C" void kernel_launch(void* const* d_in, const int* in_sizes, int n_in,
                              void* d_out, int out_size, void* d_ws, size_t ws_size,
                              hipStream_t stream) {
    const float* X     = (const float*)d_in[0];
    const int*   vid   = (const int*)d_in[1];
    const int*   eid   = (const int*)d_in[2];
    const float* W     = (const float*)d_in[3];
    const float* b     = (const float*)d_in[4];
    const float* gamma = (const float*)d_in[5];
    const float* beta  = (const float*)d_in[6];
    float* out = (float*)d_out;

    // workspace layout
    char* ws = (char*)d_ws;
    unsigned* h_u   = (unsigned*)ws;  ws += (size_t)N_V * 64 * 4;            // 25.6 MB
    unsigned* xe_u  = (unsigned*)ws;  ws += (size_t)N_E * 64 * 4;            //  5.1 MB
    unsigned* partE = (unsigned*)ws;  ws += (size_t)NB_E * EB_REGION * 4;    // 11.5 MB
    unsigned* partV = (unsigned*)ws;  ws += (size_t)NB_V * VB_REGION * 4;    // 12.8 MB
    unsigned* csrE  = (unsigned*)ws;  ws += (size_t)NB_E * EB_SORT * 4;      //  7.4 MB
    unsigned* csrV  = (unsigned*)ws;  ws += (size_t)NB_V * VB_SORT * 4;      //  7.2 MB
    int* eoff = (int*)ws;             ws += (size_t)N_E * 4;
    int* ecnt = (int*)ws;             ws += (size_t)N_E * 4;
    int* voff = (int*)ws;             ws += (size_t)N_V * 4;
    int* vcnt = (int*)ws;             ws += (size_t)N_V * 4;
    // --- zeroed region ---
    char* zbase = ws;
    int*   gcntE = (int*)ws;          ws += (size_t)NB_E * 4;
    int*   gcntV = (int*)ws;          ws += (size_t)NB_V * 4;
    float* sums  = (float*)ws;        ws += 256 * 4;
    // --- end zeroed region ---
    char* zend = ws;

    hipMemsetAsync(zbase, 0, (size_t)(zend - zbase), stream);

    // K1: gemm || sortE || sortV (independent chains, fused for concurrency)
    k_gemm_sort<<<GEMM_BLOCKS + 2 * SORT_BLOCKS, 256, 0, stream>>>(
        X, W, b, h_u, vid, eid, gcntE, gcntV, partE, partV);

    // K2: bn_stats || csrE || csrV (all depend only on K1)
    k_bn_csr<<<BN_BLOCKS + NB_E + NB_V, 256, 0, stream>>>(
        h_u, sums, partE, gcntE, eoff, ecnt, csrE,
        partV, gcntV, voff, vcnt, csrV);

    // edge: 2 channel-halves x (N_E/4) groups; blockIdx%8 pins XCD,
    // XCDs 0-3 -> half 0, XCDs 4-7 -> half 1.  BN finalize inlined.
    k_edge_gather<<<(N_E / 4) * 2, 256, 0, stream>>>(h_u, csrE, eoff, ecnt,
                                                     sums, gamma, beta, xe_u);
    // vertex: full-row, one wave per vertex
    k_vert_gather<<<(N_V + 3) / 4, 256, 0, stream>>>(xe_u, csrV, voff, vcnt,
                                                     out);
}